// Round 9
// baseline (196.600 us; speedup 1.0000x reference)
//
#include <hip/hip_runtime.h>
#include <hip/hip_bf16.h>
#include <math.h>

typedef __bf16 bf16_t;
typedef __bf16 bf16x8 __attribute__((ext_vector_type(8)));
typedef __bf16 bf16x4 __attribute__((ext_vector_type(4)));
typedef float  f32x4  __attribute__((ext_vector_type(4)));
typedef float  f32x16 __attribute__((ext_vector_type(16)));

#define D_MODEL 1024
#define NH      16
#define HD      64
#define BATCH   2
#define SEQ     2048
#define MROWS   (BATCH*SEQ)   // 4096
#define QKVN    (3*D_MODEL)   // 3072
#define FA_PAD  72            // K/V LDS row stride (elems): 144B, 16B-mult
#define SCALE_LOG2E 0.18033688011112042f   // 0.125 * log2(e), folded into Q in rope

__device__ __forceinline__ void async_cp16(const bf16_t* g, bf16_t* l) {
    __builtin_amdgcn_global_load_lds(
        (const __attribute__((address_space(1))) void*)g,
        (__attribute__((address_space(3))) void*)l,
        16, 0, 0);
}

// bare v_exp_f32 (2^x): exp2f's libm guard code is ~6 VALU insts per call
__device__ __forceinline__ float fexp2(float x) {
    float r;
    asm("v_exp_f32 %0, %1" : "=v"(r) : "v"(x));
    return r;
}

// pack two f32 -> one u32 of 2 bf16 (lo = first arg)
__device__ __forceinline__ unsigned cvtpk(float lo, float hi_) {
    unsigned r;
    asm("v_cvt_pk_bf16_f32 %0, %1, %2" : "=v"(r) : "v"(lo), "v"(hi_));
    return r;
}

// ---------------- fp32 -> bf16 convert, all three inputs in one launch ------
__global__ void cvt_all(const float* __restrict__ x, const float* __restrict__ wq,
                        const float* __restrict__ wo,
                        bf16_t* __restrict__ xb, bf16_t* __restrict__ wqb,
                        bf16_t* __restrict__ wob) {
    const int nx = MROWS * D_MODEL, nq = QKVN * D_MODEL;
    int i = (blockIdx.x * blockDim.x + threadIdx.x) * 4;
    const float* s; bf16_t* d; int off;
    if (i < nx)           { s = x;  d = xb;  off = i; }
    else if (i < nx + nq) { s = wq; d = wqb; off = i - nx; }
    else                  { s = wo; d = wob; off = i - nx - nq; }
    float4 v = *(const float4*)(s + off);
    d[off]     = (bf16_t)v.x;
    d[off + 1] = (bf16_t)v.y;
    d[off + 2] = (bf16_t)v.z;
    d[off + 3] = (bf16_t)v.w;
}

// ---------------- NT GEMM (m97 recipe): C[M,N] = A[M,K] * B[N,K]^T ----------
template <typename OutT, int NI>
__global__ __launch_bounds__(256) void gemm_nt(const bf16_t* __restrict__ A,
                                               const bf16_t* __restrict__ Bm,
                                               OutT* __restrict__ C,
                                               int M, int N, int K) {
    __shared__ __align__(16) bf16_t As[128 * 32];
    __shared__ __align__(16) bf16_t Bs[NI * 32 * 32];
    const int tid  = threadIdx.x;
    const int w    = tid >> 6;
    const int lane = tid & 63;
    const int quad = lane >> 4;
    const int l16  = lane & 15;
    const int m0   = blockIdx.x * 128;
    const int n0   = blockIdx.y * (NI * 32);
    const int wm   = (w >> 1) * 64;
    const int wn   = (w & 1) * (NI * 16);

    f32x4 acc[4][NI];
    #pragma unroll
    for (int i = 0; i < 4; i++)
        #pragma unroll
        for (int j = 0; j < NI; j++)
            acc[i][j] = (f32x4){0.f, 0.f, 0.f, 0.f};

    const bf16_t* Ag0 = A  + (size_t)(m0 + (tid >> 2)) * K + (tid & 3) * 8;
    const bf16_t* Ag1 = Ag0 + (size_t)64 * K;
    const bf16_t* Bg0 = Bm + (size_t)(n0 + (tid >> 2)) * K + (tid & 3) * 8;
    const bf16_t* Bg1 = Bg0 + (size_t)64 * K;
    bf16_t* Al0 = &As[(size_t)tid * 8];
    bf16_t* Al1 = &As[((size_t)tid + 256) * 8];
    bf16_t* Bl0 = &Bs[(size_t)tid * 8];
    bf16_t* Bl1 = &Bs[((size_t)tid + 256) * 8];

    for (int k0 = 0; k0 < K; k0 += 32) {
        async_cp16(Ag0 + k0, Al0);
        async_cp16(Ag1 + k0, Al1);
        async_cp16(Bg0 + k0, Bl0);
        if (NI == 4) async_cp16(Bg1 + k0, Bl1);
        __syncthreads();

        bf16x8 af[4], bfr[NI];
        #pragma unroll
        for (int mi = 0; mi < 4; mi++)
            af[mi] = *(const bf16x8*)&As[(wm + mi * 16 + l16) * 32 + quad * 8];
        #pragma unroll
        for (int ni = 0; ni < NI; ni++)
            bfr[ni] = *(const bf16x8*)&Bs[(wn + ni * 16 + l16) * 32 + quad * 8];
        #pragma unroll
        for (int mi = 0; mi < 4; mi++)
            #pragma unroll
            for (int ni = 0; ni < NI; ni++)
                acc[mi][ni] = __builtin_amdgcn_mfma_f32_16x16x32_bf16(
                    af[mi], bfr[ni], acc[mi][ni], 0, 0, 0);
        __syncthreads();
    }

    #pragma unroll
    for (int mi = 0; mi < 4; mi++)
        #pragma unroll
        for (int ni = 0; ni < NI; ni++) {
            const int col = n0 + wn + ni * 16 + l16;
            #pragma unroll
            for (int r = 0; r < 4; r++) {
                const int row = m0 + wm + mi * 16 + quad * 4 + r;
                C[(size_t)row * N + col] = (OutT)acc[mi][ni][r];
            }
        }
}

// ---------------- RoPE + head split + V transpose (coalesced) ----------------
// Q additionally pre-scaled by 0.125*log2(e): flash's softmax becomes a bare
// exp2 (one f32 mul here before the bf16 cvt = same single rounding).
__global__ __launch_bounds__(256) void rope_split(const bf16_t* __restrict__ qkv,
                                                  const int* __restrict__ pos,
                                                  bf16_t* __restrict__ Qh,
                                                  bf16_t* __restrict__ Kh,
                                                  bf16_t* __restrict__ VT) {
    __shared__ bf16_t vs[128][FA_PAD];
    const int tid   = threadIdx.x;
    const int s_loc = tid >> 1;
    const int half  = tid & 1;
    const int s0    = blockIdx.x * 128;
    const int bh    = blockIdx.y;
    const int b     = bh >> 4, h = bh & 15;
    const int s     = s0 + s_loc;

    const bf16_t* row = qkv + (size_t)(b * SEQ + s) * QKVN + h * HD + half * 32;

    bf16_t qbuf[32], kbuf[32], vbuf[32];
    #pragma unroll
    for (int j = 0; j < 4; j++) {
        *(bf16x8*)&qbuf[j * 8] = *(const bf16x8*)(row + j * 8);
        *(bf16x8*)&kbuf[j * 8] = *(const bf16x8*)(row + D_MODEL + j * 8);
        *(bf16x8*)&vbuf[j * 8] = *(const bf16x8*)(row + 2 * D_MODEL + j * 8);
    }

    const float pf = (float)pos[s];
    #pragma unroll
    for (int p = 0; p < 16; p++) {
        const int d2 = half * 16 + p;
        const float inv = __expf(-0.28782313662425575f * (float)d2);
        const float f = pf * inv;
        const float c = cosf(f), sn = sinf(f);
        float qe = (float)qbuf[2 * p], qo = (float)qbuf[2 * p + 1];
        float ke = (float)kbuf[2 * p], ko = (float)kbuf[2 * p + 1];
        qbuf[2 * p]     = (bf16_t)((qe * c - qo * sn) * SCALE_LOG2E);
        qbuf[2 * p + 1] = (bf16_t)((qo * c + qe * sn) * SCALE_LOG2E);
        kbuf[2 * p]     = (bf16_t)(ke * c - ko * sn);
        kbuf[2 * p + 1] = (bf16_t)(ko * c + ke * sn);
    }

    bf16_t* qdst = Qh + ((size_t)bh * SEQ + s) * HD + half * 32;
    bf16_t* kdst = Kh + ((size_t)bh * SEQ + s) * HD + half * 32;
    #pragma unroll
    for (int j = 0; j < 4; j++) {
        *(bf16x8*)(qdst + j * 8) = *(bf16x8*)&qbuf[j * 8];
        *(bf16x8*)(kdst + j * 8) = *(bf16x8*)&kbuf[j * 8];
        *(bf16x8*)&vs[s_loc][half * 32 + j * 8] = *(bf16x8*)&vbuf[j * 8];
    }
    __syncthreads();

    const int d  = tid >> 2;
    const int sc = tid & 3;
    bf16_t tmp[32];
    #pragma unroll
    for (int i = 0; i < 32; i++) tmp[i] = vs[sc * 32 + i][d];
    bf16_t* vdst = VT + ((size_t)bh * HD + d) * SEQ + s0 + sc * 32;
    #pragma unroll
    for (int j = 0; j < 4; j++)
        *(bf16x8*)(vdst + j * 8) = *(bf16x8*)&tmp[j * 8];
}

// ---------------- causal flash attention: paired tiles, 2 chains per wave ---
// 512 blocks x 256 thr (4 waves). Block owns q-tile PAIR {tA=31-u, tB=u}; the
// kv loop stages tiles 0..tA (r8 dbuf shell, 1 barrier/iter). Every wave
// computes its 32x32 quadrant for tile A and, while kt <= tB, for tile B.
// The two quadrants SHARE the staged K/V and the kb/vf LDS reads (2x amortize)
// and form two independent MFMA->exp->pack->MFMA chains that fill each
// other's latency (r8 diagnosis: dependency-chain-bound at ~2 live blocks/CU
// from retirement decay). Work/block = (32-u)+(u+1) = 33 uniform; barriers
// per unit work halved. P stays in registers (T12 cvt_pk + permlane32_swap).
__global__ __launch_bounds__(256) void flash_attn(const bf16_t* __restrict__ Qh,
                                                  const bf16_t* __restrict__ Kh,
                                                  const bf16_t* __restrict__ VT,
                                                  bf16_t* __restrict__ AO) {
    // loop:  Ks[2][64][72] | Vs[2][64][72]  (36.9 KB)
    // merge: mrgO[2tile][2qh][32][66] f32 (33.8 KB) + lsp[2][64] f32, aliased
    __shared__ __align__(16) bf16_t smem[4 * 64 * FA_PAD];
    bf16_t* Ks0 = smem;                       // Ks[0], Ks[1], Vs[0], Vs[1]
    bf16_t* Vs0 = smem + 2 * 64 * FA_PAD;
    const int BUF = 64 * FA_PAD;

    const int tid  = threadIdx.x;
    const int w    = tid >> 6;
    const int lane = tid & 63;
    const int l31  = lane & 31;
    const int hi   = lane >> 5;
    const int qh   = w & 1;         // q-half of each 64-row tile
    const int kh   = w >> 1;        // kv-half of each 64-kv iter tile

    const int bid  = blockIdx.x;
    const int bh   = bid & 31;      // bid%8 == bh%8 -> same-bh blocks same XCD
    const int u    = bid >> 5;      // 0..15; longest pairs dispatch first
    const int tA   = 31 - u;        // long tile (sets the wall)
    const int tB   = u;             // short tile (rides the kv prefix)
    const int nkv  = tA + 1;        // 17..32 iters

    const bf16_t* Qb = Qh + (size_t)bh * SEQ * HD;
    const bf16_t* Kb = Kh + (size_t)bh * SEQ * HD;
    const bf16_t* Vb = VT + (size_t)bh * HD * SEQ;

    const int qloA = tA * 64 + qh * 32, qgA = qloA + l31;
    const int qloB = tB * 64 + qh * 32, qgB = qloB + l31;

    // Q B-frags (4 k-slots of HD): B[k=ks*16+hi*8+e][col=q=l31], per tile
    bf16x8 aqA[4], aqB[4];
    #pragma unroll
    for (int ks = 0; ks < 4; ks++) {
        aqA[ks] = *(const bf16x8*)(Qb + (size_t)qgA * HD + ks * 16 + hi * 8);
        aqB[ks] = *(const bf16x8*)(Qb + (size_t)qgB * HD + ks * 16 + hi * 8);
    }

    // staging: 256 threads, 2 rows each per tensor (coalesced 128B rows)
    const int srow = tid >> 3, scol = (tid & 7) * 8;
    const int lds0 = srow * FA_PAD + scol;
    const int lds1 = (srow + 32) * FA_PAD + scol;

    f32x16 oA[2], oB[2];
    #pragma unroll
    for (int dt = 0; dt < 2; dt++)
        #pragma unroll
        for (int i = 0; i < 16; i++) { oA[dt][i] = 0.f; oB[dt][i] = 0.f; }
    float lsA = 0.f, lsB = 0.f;

    // prologue: load tile 0 to regs, write into buf 0
    bf16x8 pK0 = *(const bf16x8*)(Kb + (size_t)srow * HD + scol);
    bf16x8 pK1 = *(const bf16x8*)(Kb + (size_t)(srow + 32) * HD + scol);
    bf16x8 pV0 = *(const bf16x8*)(Vb + (size_t)srow * SEQ + scol);
    bf16x8 pV1 = *(const bf16x8*)(Vb + (size_t)(srow + 32) * SEQ + scol);
    *(bf16x8*)&Ks0[lds0] = pK0;
    *(bf16x8*)&Ks0[lds1] = pK1;
    *(bf16x8*)&Vs0[lds0] = pV0;
    *(bf16x8*)&Vs0[lds1] = pV1;

// one 32x32 quadrant: S^T = mfma(K,Q), exp, mask, pack-in-regs, PV accumulate.
// kb[] / vfr[][] are ambient (shared between the two tiles of the pair).
#define QUAD(AQ, QG, O, LS, FULL) {                                            \
    f32x16 t;                                                                  \
    _Pragma("unroll")                                                          \
    for (int i = 0; i < 16; i++) t[i] = 0.f;                                   \
    _Pragma("unroll")                                                          \
    for (int ks = 0; ks < 4; ks++)                                             \
        t = __builtin_amdgcn_mfma_f32_32x32x16_bf16(kb[ks], AQ[ks], t, 0, 0, 0); \
    float pv[16];                                                              \
    _Pragma("unroll")                                                          \
    for (int r = 0; r < 16; r++) {                                             \
        float p = fexp2(t[r]);                                                 \
        if (!(FULL)) {                                                         \
            const int kvg = kvbw + (r & 3) + 8 * (r >> 2) + 4 * hi;            \
            if (kvg > (QG)) p = 0.f;                                           \
        }                                                                      \
        pv[r] = p;                                                             \
    }                                                                          \
    LS += ((((pv[0] + pv[1]) + (pv[2] + pv[3]))                                \
          + ((pv[4] + pv[5]) + (pv[6] + pv[7])))                               \
         + (((pv[8] + pv[9]) + (pv[10] + pv[11]))                              \
          + ((pv[12] + pv[13]) + (pv[14] + pv[15]))));                         \
    union { unsigned uu[4]; bf16x8 v; } pa0, pa1;                              \
    {                                                                          \
        unsigned a0 = cvtpk(pv[0], pv[1]);                                     \
        unsigned b0 = cvtpk(pv[4], pv[5]);                                     \
        unsigned a1 = cvtpk(pv[2], pv[3]);                                     \
        unsigned b1 = cvtpk(pv[6], pv[7]);                                     \
        asm volatile("v_permlane32_swap_b32 %0, %1" : "+v"(a0), "+v"(b0));     \
        asm volatile("v_permlane32_swap_b32 %0, %1" : "+v"(a1), "+v"(b1));     \
        pa0.uu[0] = a0; pa0.uu[1] = a1; pa0.uu[2] = b0; pa0.uu[3] = b1;        \
    }                                                                          \
    {                                                                          \
        unsigned a0 = cvtpk(pv[8], pv[9]);                                     \
        unsigned b0 = cvtpk(pv[12], pv[13]);                                   \
        unsigned a1 = cvtpk(pv[10], pv[11]);                                   \
        unsigned b1 = cvtpk(pv[14], pv[15]);                                   \
        asm volatile("v_permlane32_swap_b32 %0, %1" : "+v"(a0), "+v"(b0));     \
        asm volatile("v_permlane32_swap_b32 %0, %1" : "+v"(a1), "+v"(b1));     \
        pa1.uu[0] = a0; pa1.uu[1] = a1; pa1.uu[2] = b0; pa1.uu[3] = b1;        \
    }                                                                          \
    _Pragma("unroll")                                                          \
    for (int dt = 0; dt < 2; dt++) {                                           \
        O[dt] = __builtin_amdgcn_mfma_f32_32x32x16_bf16(pa0.v, vfr[dt][0], O[dt], 0, 0, 0); \
        O[dt] = __builtin_amdgcn_mfma_f32_32x32x16_bf16(pa1.v, vfr[dt][1], O[dt], 0, 0, 0); \
    }                                                                          \
}

    for (int kt = 0; kt < nkv; ++kt) {
        const int cur = kt & 1;
        __syncthreads();   // buf[cur] fully written; all reads of buf[cur^1] done

        // prefetch next tile to regs: HBM/L2 latency hides under compute
        if (kt + 1 < nkv) {
            const int kn = (kt + 1) * 64;
            pK0 = *(const bf16x8*)(Kb + (size_t)(kn + srow) * HD + scol);
            pK1 = *(const bf16x8*)(Kb + (size_t)(kn + srow + 32) * HD + scol);
            pV0 = *(const bf16x8*)(Vb + (size_t)srow * SEQ + kn + scol);
            pV1 = *(const bf16x8*)(Vb + (size_t)(srow + 32) * SEQ + kn + scol);
        }

        const bf16_t* KsC = Ks0 + cur * BUF;
        const bf16_t* VsC = Vs0 + cur * BUF;
        const int kvbw = kt * 64 + kh * 32;            // wave's kv-quadrant base
        const bool actA = (kvbw <= qloA + 31);
        const bool actB = (kt <= tB) && (kvbw <= qloB + 31);

        if (actA || actB) {
            // shared fragment loads (amortized over both tiles)
            bf16x8 kb[4];
            #pragma unroll
            for (int ks = 0; ks < 4; ks++)
                kb[ks] = *(const bf16x8*)&KsC[(kh * 32 + l31) * FA_PAD + ks * 16 + hi * 8];
            bf16x8 vfr[2][2];
            #pragma unroll
            for (int dt = 0; dt < 2; dt++) {
                const int vbase = (dt * 32 + l31) * FA_PAD + kh * 32 + hi * 8;
                vfr[dt][0] = *(const bf16x8*)&VsC[vbase];
                vfr[dt][1] = *(const bf16x8*)&VsC[vbase + 16];
            }
            if (actA) {
                const bool fullA = (kvbw + 31 <= qloA);
                QUAD(aqA, qgA, oA, lsA, fullA);
            }
            if (actB) {
                const bool fullB = (kvbw + 31 <= qloB);
                QUAD(aqB, qgB, oB, lsB, fullB);
            }
        }

        // write prefetched tile into the other buffer (ready at next barrier)
        if (kt + 1 < nkv) {
            bf16_t* KsN = Ks0 + (cur ^ 1) * BUF;
            bf16_t* VsN = Vs0 + (cur ^ 1) * BUF;
            *(bf16x8*)&KsN[lds0] = pK0;
            *(bf16x8*)&KsN[lds1] = pK1;
            *(bf16x8*)&VsN[lds0] = pV0;
            *(bf16x8*)&VsN[lds1] = pV1;
        }
    }
#undef QUAD

    // ---- merge the two kv-half waves per (tile, q-half) via LDS ----
    __syncthreads();                 // all compute done before aliasing
    lsA += __shfl_xor(lsA, 32);      // combine hi halves: per-lane sum for q=l31
    lsB += __shfl_xor(lsB, 32);
    float* mrgO = (float*)smem;      // [tile][qh][32][66]
    float* lsp  = mrgO + 4 * 32 * 66;   // [tile][qh*32+l31]
    if (kh == 1) {
        #pragma unroll
        for (int r = 0; r < 16; r++) {
            const int qlc = (r & 3) + 8 * (r >> 2) + 4 * hi;
            #pragma unroll
            for (int dt = 0; dt < 2; dt++) {
                mrgO[((0 * 2 + qh) * 32 + qlc) * 66 + dt * 32 + l31] = oA[dt][r];
                mrgO[((1 * 2 + qh) * 32 + qlc) * 66 + dt * 32 + l31] = oB[dt][r];
            }
        }
        if (hi == 0) {
            lsp[0 * 64 + qh * 32 + l31] = lsA;
            lsp[1 * 64 + qh * 32 + l31] = lsB;
        }
    }
    __syncthreads();
    if (kh == 0) {
        const int b = bh >> 4, hh = bh & 15;
        const float ltA = lsA + lsp[0 * 64 + qh * 32 + l31];
        const float ltB = lsB + lsp[1 * 64 + qh * 32 + l31];
        #pragma unroll
        for (int r = 0; r < 16; r++) {
            const int qlc = (r & 3) + 8 * (r >> 2) + 4 * hi;
            const float liA = 1.0f / __shfl(ltA, qlc);
            const float liB = 1.0f / __shfl(ltB, qlc);
            const size_t rowA = (size_t)b * SEQ + tA * 64 + qh * 32 + qlc;
            const size_t rowB = (size_t)b * SEQ + tB * 64 + qh * 32 + qlc;
            #pragma unroll
            for (int dt = 0; dt < 2; dt++) {
                const float vA = oA[dt][r] + mrgO[((0 * 2 + qh) * 32 + qlc) * 66 + dt * 32 + l31];
                const float vB = oB[dt][r] + mrgO[((1 * 2 + qh) * 32 + qlc) * 66 + dt * 32 + l31];
                AO[rowA * D_MODEL + hh * HD + dt * 32 + l31] = (bf16_t)(vA * liA);
                AO[rowB * D_MODEL + hh * HD + dt * 32 + l31] = (bf16_t)(vB * liB);
            }
        }
    }
}

// ---------------- launcher ----------------
extern "C" void kernel_launch(void* const* d_in, const int* in_sizes, int n_in,
                              void* d_out, int out_size, void* d_ws, size_t ws_size,
                              hipStream_t stream) {
    const float* x     = (const float*)d_in[0];
    const float* w_qkv = (const float*)d_in[1];
    const float* w_o   = (const float*)d_in[2];
    const int*   tpos  = (const int*)d_in[3];
    float*       out   = (float*)d_out;

    char* ws = (char*)d_ws;
    bf16_t* xb  = (bf16_t*)(ws);                 //  8 MB
    bf16_t* wqb = (bf16_t*)(ws + 8388608);       //  6 MB
    bf16_t* wob = (bf16_t*)(ws + 14680064);      //  2 MB
    bf16_t* qkv = (bf16_t*)(ws + 16777216);      // 24 MB
    bf16_t* Qh  = (bf16_t*)(ws + 41943040);      //  8 MB
    bf16_t* Kh  = (bf16_t*)(ws + 50331648);      //  8 MB
    bf16_t* VT  = (bf16_t*)(ws + 58720256);      //  8 MB
    bf16_t* AO  = (bf16_t*)(ws + 67108864);      //  8 MB

    cvt_all<<<8192, 256, 0, stream>>>(x, w_qkv, w_o, xb, wqb, wob);

    // qkv = x @ w_qkv^T : M=4096, N=3072, K=1024
    gemm_nt<bf16_t, 4><<<dim3(32, 24), 256, 0, stream>>>(xb, wqb, qkv, MROWS, QKVN, D_MODEL);

    rope_split<<<dim3(SEQ / 128, BATCH * NH), 256, 0, stream>>>(qkv, tpos, Qh, Kh, VT);

    flash_attn<<<512, 256, 0, stream>>>(Qh, Kh, VT, AO);

    // out = AO @ w_o^T : M=4096, N=1024, K=1024 (fp32 out)
    gemm_nt<float, 2><<<dim3(32, 16), 256, 0, stream>>>(AO, wob, out, MROWS, D_MODEL, D_MODEL);
}

// Round 10
// 183.908 us; speedup vs baseline: 1.0690x; 1.0690x over previous
//
#include <hip/hip_runtime.h>
#include <hip/hip_bf16.h>
#include <math.h>

typedef __bf16 bf16_t;
typedef __bf16 bf16x8 __attribute__((ext_vector_type(8)));
typedef __bf16 bf16x4 __attribute__((ext_vector_type(4)));
typedef float  f32x4  __attribute__((ext_vector_type(4)));
typedef float  f32x16 __attribute__((ext_vector_type(16)));

#define D_MODEL 1024
#define NH      16
#define HD      64
#define BATCH   2
#define SEQ     2048
#define MROWS   (BATCH*SEQ)   // 4096
#define QKVN    (3*D_MODEL)   // 3072
#define FA_PAD  72            // K/V LDS row stride (elems): 144B, 16B-mult
#define SCALE_LOG2E 0.18033688011112042f   // 0.125 * log2(e), folded into Q in rope

__device__ __forceinline__ void async_cp16(const bf16_t* g, bf16_t* l) {
    __builtin_amdgcn_global_load_lds(
        (const __attribute__((address_space(1))) void*)g,
        (__attribute__((address_space(3))) void*)l,
        16, 0, 0);
}

// bare v_exp_f32 (2^x): exp2f's libm guard code is ~6 VALU insts per call
__device__ __forceinline__ float fexp2(float x) {
    float r;
    asm("v_exp_f32 %0, %1" : "=v"(r) : "v"(x));
    return r;
}

// pack two f32 -> one u32 of 2 bf16 (lo = first arg)
__device__ __forceinline__ unsigned cvtpk(float lo, float hi_) {
    unsigned r;
    asm("v_cvt_pk_bf16_f32 %0, %1, %2" : "=v"(r) : "v"(lo), "v"(hi_));
    return r;
}

// ---------------- fp32 -> bf16 convert, all three inputs in one launch ------
__global__ void cvt_all(const float* __restrict__ x, const float* __restrict__ wq,
                        const float* __restrict__ wo,
                        bf16_t* __restrict__ xb, bf16_t* __restrict__ wqb,
                        bf16_t* __restrict__ wob) {
    const int nx = MROWS * D_MODEL, nq = QKVN * D_MODEL;
    int i = (blockIdx.x * blockDim.x + threadIdx.x) * 4;
    const float* s; bf16_t* d; int off;
    if (i < nx)           { s = x;  d = xb;  off = i; }
    else if (i < nx + nq) { s = wq; d = wqb; off = i - nx; }
    else                  { s = wo; d = wob; off = i - nx - nq; }
    float4 v = *(const float4*)(s + off);
    d[off]     = (bf16_t)v.x;
    d[off + 1] = (bf16_t)v.y;
    d[off + 2] = (bf16_t)v.z;
    d[off + 3] = (bf16_t)v.w;
}

// ------- NT GEMM, BK=64 via two proven [128][32] sub-slabs ------------------
// m97 recipe shell, but each iteration stages TWO 32-K slabs (separate LDS
// buffers, each with the conflict-free 64B row stride) and runs 32 MFMA per
// wave between one barrier pair. Halves the vmcnt(0)+barrier drains per K —
// the m97 structure's known ~20% stall — without touching the proven bank
// layout (monolithic [128][64] would be a 16-way conflict, G4).
template <typename OutT, int NI>
__global__ __launch_bounds__(256) void gemm_nt(const bf16_t* __restrict__ A,
                                               const bf16_t* __restrict__ Bm,
                                               OutT* __restrict__ C,
                                               int M, int N, int K) {
    __shared__ __align__(16) bf16_t AsA[128 * 32], AsB[128 * 32];
    __shared__ __align__(16) bf16_t BsA[NI * 32 * 32], BsB[NI * 32 * 32];
    const int tid  = threadIdx.x;
    const int w    = tid >> 6;
    const int lane = tid & 63;
    const int quad = lane >> 4;
    const int l16  = lane & 15;
    const int m0   = blockIdx.x * 128;
    const int n0   = blockIdx.y * (NI * 32);
    const int wm   = (w >> 1) * 64;
    const int wn   = (w & 1) * (NI * 16);

    f32x4 acc[4][NI];
    #pragma unroll
    for (int i = 0; i < 4; i++)
        #pragma unroll
        for (int j = 0; j < NI; j++)
            acc[i][j] = (f32x4){0.f, 0.f, 0.f, 0.f};

    const bf16_t* Ag0 = A  + (size_t)(m0 + (tid >> 2)) * K + (tid & 3) * 8;
    const bf16_t* Ag1 = Ag0 + (size_t)64 * K;
    const bf16_t* Bg0 = Bm + (size_t)(n0 + (tid >> 2)) * K + (tid & 3) * 8;
    const bf16_t* Bg1 = Bg0 + (size_t)64 * K;

    for (int k0 = 0; k0 < K; k0 += 64) {
        // slab A: k0..k0+31, slab B: k0+32..k0+63 (same proven per-slab map)
        async_cp16(Ag0 + k0,      &AsA[(size_t)tid * 8]);
        async_cp16(Ag1 + k0,      &AsA[((size_t)tid + 256) * 8]);
        async_cp16(Ag0 + k0 + 32, &AsB[(size_t)tid * 8]);
        async_cp16(Ag1 + k0 + 32, &AsB[((size_t)tid + 256) * 8]);
        async_cp16(Bg0 + k0,      &BsA[(size_t)tid * 8]);
        async_cp16(Bg0 + k0 + 32, &BsB[(size_t)tid * 8]);
        if (NI == 4) {
            async_cp16(Bg1 + k0,      &BsA[((size_t)tid + 256) * 8]);
            async_cp16(Bg1 + k0 + 32, &BsB[((size_t)tid + 256) * 8]);
        }
        __syncthreads();

        bf16x8 af[4][2], bfr[NI][2];
        #pragma unroll
        for (int mi = 0; mi < 4; mi++) {
            af[mi][0] = *(const bf16x8*)&AsA[(wm + mi * 16 + l16) * 32 + quad * 8];
            af[mi][1] = *(const bf16x8*)&AsB[(wm + mi * 16 + l16) * 32 + quad * 8];
        }
        #pragma unroll
        for (int ni = 0; ni < NI; ni++) {
            bfr[ni][0] = *(const bf16x8*)&BsA[(wn + ni * 16 + l16) * 32 + quad * 8];
            bfr[ni][1] = *(const bf16x8*)&BsB[(wn + ni * 16 + l16) * 32 + quad * 8];
        }
        #pragma unroll
        for (int mi = 0; mi < 4; mi++)
            #pragma unroll
            for (int ni = 0; ni < NI; ni++) {
                acc[mi][ni] = __builtin_amdgcn_mfma_f32_16x16x32_bf16(
                    af[mi][0], bfr[ni][0], acc[mi][ni], 0, 0, 0);
                acc[mi][ni] = __builtin_amdgcn_mfma_f32_16x16x32_bf16(
                    af[mi][1], bfr[ni][1], acc[mi][ni], 0, 0, 0);
            }
        __syncthreads();
    }

    #pragma unroll
    for (int mi = 0; mi < 4; mi++)
        #pragma unroll
        for (int ni = 0; ni < NI; ni++) {
            const int col = n0 + wn + ni * 16 + l16;
            #pragma unroll
            for (int r = 0; r < 4; r++) {
                const int row = m0 + wm + mi * 16 + quad * 4 + r;
                C[(size_t)row * N + col] = (OutT)acc[mi][ni][r];
            }
        }
}

// ---------------- RoPE + head split + V transpose (coalesced) ----------------
// Q additionally pre-scaled by 0.125*log2(e): flash's softmax becomes a bare
// exp2 (one f32 mul here before the bf16 cvt = same single rounding).
__global__ __launch_bounds__(256) void rope_split(const bf16_t* __restrict__ qkv,
                                                  const int* __restrict__ pos,
                                                  bf16_t* __restrict__ Qh,
                                                  bf16_t* __restrict__ Kh,
                                                  bf16_t* __restrict__ VT) {
    __shared__ bf16_t vs[128][FA_PAD];
    const int tid   = threadIdx.x;
    const int s_loc = tid >> 1;
    const int half  = tid & 1;
    const int s0    = blockIdx.x * 128;
    const int bh    = blockIdx.y;
    const int b     = bh >> 4, h = bh & 15;
    const int s     = s0 + s_loc;

    const bf16_t* row = qkv + (size_t)(b * SEQ + s) * QKVN + h * HD + half * 32;

    bf16_t qbuf[32], kbuf[32], vbuf[32];
    #pragma unroll
    for (int j = 0; j < 4; j++) {
        *(bf16x8*)&qbuf[j * 8] = *(const bf16x8*)(row + j * 8);
        *(bf16x8*)&kbuf[j * 8] = *(const bf16x8*)(row + D_MODEL + j * 8);
        *(bf16x8*)&vbuf[j * 8] = *(const bf16x8*)(row + 2 * D_MODEL + j * 8);
    }

    const float pf = (float)pos[s];
    #pragma unroll
    for (int p = 0; p < 16; p++) {
        const int d2 = half * 16 + p;
        const float inv = __expf(-0.28782313662425575f * (float)d2);
        const float f = pf * inv;
        const float c = cosf(f), sn = sinf(f);
        float qe = (float)qbuf[2 * p], qo = (float)qbuf[2 * p + 1];
        float ke = (float)kbuf[2 * p], ko = (float)kbuf[2 * p + 1];
        qbuf[2 * p]     = (bf16_t)((qe * c - qo * sn) * SCALE_LOG2E);
        qbuf[2 * p + 1] = (bf16_t)((qo * c + qe * sn) * SCALE_LOG2E);
        kbuf[2 * p]     = (bf16_t)(ke * c - ko * sn);
        kbuf[2 * p + 1] = (bf16_t)(ko * c + ke * sn);
    }

    bf16_t* qdst = Qh + ((size_t)bh * SEQ + s) * HD + half * 32;
    bf16_t* kdst = Kh + ((size_t)bh * SEQ + s) * HD + half * 32;
    #pragma unroll
    for (int j = 0; j < 4; j++) {
        *(bf16x8*)(qdst + j * 8) = *(bf16x8*)&qbuf[j * 8];
        *(bf16x8*)(kdst + j * 8) = *(bf16x8*)&kbuf[j * 8];
        *(bf16x8*)&vs[s_loc][half * 32 + j * 8] = *(bf16x8*)&vbuf[j * 8];
    }
    __syncthreads();

    const int d  = tid >> 2;
    const int sc = tid & 3;
    bf16_t tmp[32];
    #pragma unroll
    for (int i = 0; i < 32; i++) tmp[i] = vs[sc * 32 + i][d];
    bf16_t* vdst = VT + ((size_t)bh * HD + d) * SEQ + s0 + sc * 32;
    #pragma unroll
    for (int j = 0; j < 4; j++)
        *(bf16x8*)(vdst + j * 8) = *(bf16x8*)&tmp[j * 8];
}

// ---------------- causal flash attention: 32x32 quadrants, P-in-registers ---
// EXACT r8 kernel (best verified: 43.2 us, VGPR 76, bank conflicts = 0).
// 1024 blocks x 256 thr (4 waves), wave = (qhalf, kvhalf) quadrant of a
// 64q x 64kv tile. P never touches LDS (T12 cvt_pk + permlane32_swap);
// double-buffered K/V, ONE barrier per tile; lsum tree-summed; exp2 direct.
__global__ __launch_bounds__(256) void flash_attn(const bf16_t* __restrict__ Qh,
                                                  const bf16_t* __restrict__ Kh,
                                                  const bf16_t* __restrict__ VT,
                                                  bf16_t* __restrict__ AO) {
    // loop:  Ks[2][64][72] | Vs[2][64][72]  (36.9 KB)
    // merge: mrgO[2][32][66] f32 + lsp[64] f32 (17.2 KB) aliased at base
    __shared__ __align__(16) bf16_t smem[4 * 64 * FA_PAD];
    bf16_t* Ks0 = smem;                       // Ks[0], Ks[1], Vs[0], Vs[1]
    bf16_t* Vs0 = smem + 2 * 64 * FA_PAD;
    const int BUF = 64 * FA_PAD;

    const int tid  = threadIdx.x;
    const int w    = tid >> 6;
    const int lane = tid & 63;
    const int l31  = lane & 31;
    const int hi   = lane >> 5;
    const int qh   = w & 1;         // q-half of the 64-row tile
    const int kh   = w >> 1;        // kv-half of each 64-kv iter tile

    const int bid  = blockIdx.x;
    const int bh   = bid & 31;      // bid%8 == bh%8 -> same-bh blocks same XCD
    const int my_t = 31 - (bid >> 5);   // largest q-tiles dispatch first (LPT)
    const int nkv  = my_t + 1;      // 64-kv tiles needed (causal)

    const bf16_t* Qb = Qh + (size_t)bh * SEQ * HD;
    const bf16_t* Kb = Kh + (size_t)bh * SEQ * HD;
    const bf16_t* Vb = VT + (size_t)bh * HD * SEQ;

    const int q0b = my_t * 64;
    const int qlo = q0b + qh * 32;
    const int qg  = qlo + l31;      // my S^T column's global q row

    // Q B-frags (4 k-slots of HD): B[k=ks*16+hi*8+e][col=q=l31]
    bf16x8 aq[4];
    #pragma unroll
    for (int ks = 0; ks < 4; ks++)
        aq[ks] = *(const bf16x8*)(Qb + (size_t)qg * HD + ks * 16 + hi * 8);

    // staging: 256 threads, 2 rows each per tensor (coalesced 128B rows)
    const int srow = tid >> 3, scol = (tid & 7) * 8;
    const int lds0 = srow * FA_PAD + scol;
    const int lds1 = (srow + 32) * FA_PAD + scol;

    f32x16 o[2];
    #pragma unroll
    for (int dt = 0; dt < 2; dt++)
        #pragma unroll
        for (int i = 0; i < 16; i++) o[dt][i] = 0.f;
    float ls = 0.f;

    // prologue: load tile 0 to regs, write into buf 0
    bf16x8 pK0 = *(const bf16x8*)(Kb + (size_t)srow * HD + scol);
    bf16x8 pK1 = *(const bf16x8*)(Kb + (size_t)(srow + 32) * HD + scol);
    bf16x8 pV0 = *(const bf16x8*)(Vb + (size_t)srow * SEQ + scol);
    bf16x8 pV1 = *(const bf16x8*)(Vb + (size_t)(srow + 32) * SEQ + scol);
    *(bf16x8*)&Ks0[lds0] = pK0;
    *(bf16x8*)&Ks0[lds1] = pK1;
    *(bf16x8*)&Vs0[lds0] = pV0;
    *(bf16x8*)&Vs0[lds1] = pV1;

    for (int kt = 0; kt < nkv; ++kt) {
        const int cur = kt & 1;
        __syncthreads();   // buf[cur] fully written; all reads of buf[cur^1] done

        // prefetch next tile to regs: HBM/L2 latency hides under compute
        if (kt + 1 < nkv) {
            const int kn = (kt + 1) * 64;
            pK0 = *(const bf16x8*)(Kb + (size_t)(kn + srow) * HD + scol);
            pK1 = *(const bf16x8*)(Kb + (size_t)(kn + srow + 32) * HD + scol);
            pV0 = *(const bf16x8*)(Vb + (size_t)srow * SEQ + kn + scol);
            pV1 = *(const bf16x8*)(Vb + (size_t)(srow + 32) * SEQ + kn + scol);
        }

        const bf16_t* KsC = Ks0 + cur * BUF;
        const bf16_t* VsC = Vs0 + cur * BUF;
        const int kvbw = kt * 64 + kh * 32;    // wave's kv-quadrant base
        if (kvbw <= qlo + 31) {                // not fully masked (wave-uniform)
            const bool full = (kvbw + 31 <= qlo);

            // S^T quadrant: A = K from LDS, B = Q regs
            bf16x8 kb[4];
            #pragma unroll
            for (int ks = 0; ks < 4; ks++)
                kb[ks] = *(const bf16x8*)&KsC[(kh * 32 + l31) * FA_PAD + ks * 16 + hi * 8];
            f32x16 t;
            #pragma unroll
            for (int i = 0; i < 16; i++) t[i] = 0.f;
            #pragma unroll
            for (int ks = 0; ks < 4; ks++)
                t = __builtin_amdgcn_mfma_f32_32x32x16_bf16(kb[ks], aq[ks], t, 0, 0, 0);

            // softmax (max-free; Q pre-scaled) + causal mask
            float pv[16];
            #pragma unroll
            for (int r = 0; r < 16; r++) {
                float p = fexp2(t[r]);
                if (!full) {
                    const int kvg = kvbw + (r & 3) + 8 * (r >> 2) + 4 * hi;
                    if (kvg > qg) p = 0.f;
                }
                pv[r] = p;
            }
            // tree-sum (4-deep) into running denominator
            ls += ((((pv[0] + pv[1]) + (pv[2] + pv[3]))
                  + ((pv[4] + pv[5]) + (pv[6] + pv[7])))
                 + (((pv[8] + pv[9]) + (pv[10] + pv[11]))
                  + ((pv[12] + pv[13]) + (pv[14] + pv[15]))));

            // T12: pack + permlane32_swap -> PV A-frags entirely in registers
            union { unsigned u[4]; bf16x8 v; } pa0, pa1;
            {
                unsigned a0 = cvtpk(pv[0], pv[1]);
                unsigned b0 = cvtpk(pv[4], pv[5]);
                unsigned a1 = cvtpk(pv[2], pv[3]);
                unsigned b1 = cvtpk(pv[6], pv[7]);
                asm volatile("v_permlane32_swap_b32 %0, %1" : "+v"(a0), "+v"(b0));
                asm volatile("v_permlane32_swap_b32 %0, %1" : "+v"(a1), "+v"(b1));
                pa0.u[0] = a0; pa0.u[1] = a1; pa0.u[2] = b0; pa0.u[3] = b1;
            }
            {
                unsigned a0 = cvtpk(pv[8], pv[9]);
                unsigned b0 = cvtpk(pv[12], pv[13]);
                unsigned a1 = cvtpk(pv[10], pv[11]);
                unsigned b1 = cvtpk(pv[14], pv[15]);
                asm volatile("v_permlane32_swap_b32 %0, %1" : "+v"(a0), "+v"(b0));
                asm volatile("v_permlane32_swap_b32 %0, %1" : "+v"(a1), "+v"(b1));
                pa1.u[0] = a0; pa1.u[1] = a1; pa1.u[2] = b0; pa1.u[3] = b1;
            }

            // PV: A = P regs, B = V from Vs
            #pragma unroll
            for (int dt = 0; dt < 2; dt++) {
                const int vbase = (dt * 32 + l31) * FA_PAD + kh * 32 + hi * 8;
                bf16x8 vf0 = *(const bf16x8*)&VsC[vbase];
                bf16x8 vf1 = *(const bf16x8*)&VsC[vbase + 16];
                o[dt] = __builtin_amdgcn_mfma_f32_32x32x16_bf16(pa0.v, vf0, o[dt], 0, 0, 0);
                o[dt] = __builtin_amdgcn_mfma_f32_32x32x16_bf16(pa1.v, vf1, o[dt], 0, 0, 0);
            }
        }

        // write prefetched tile into the other buffer (ready at next barrier)
        if (kt + 1 < nkv) {
            bf16_t* KsN = Ks0 + (cur ^ 1) * BUF;
            bf16_t* VsN = Vs0 + (cur ^ 1) * BUF;
            *(bf16x8*)&KsN[lds0] = pK0;
            *(bf16x8*)&KsN[lds1] = pK1;
            *(bf16x8*)&VsN[lds0] = pV0;
            *(bf16x8*)&VsN[lds1] = pV1;
        }
    }

    // ---- merge the two kv-half waves per q-half via LDS (alias smem) ----
    __syncthreads();                 // all compute done before aliasing
    ls += __shfl_xor(ls, 32);        // combine hi halves: per-lane sum for q=l31
    float* mrgO = (float*)smem;      // [2][32][66]
    float* lsp  = mrgO + 2 * 32 * 66;
    if (kh == 1) {
        #pragma unroll
        for (int r = 0; r < 16; r++) {
            const int qlc = (r & 3) + 8 * (r >> 2) + 4 * hi;
            #pragma unroll
            for (int dt = 0; dt < 2; dt++)
                mrgO[(qh * 32 + qlc) * 66 + dt * 32 + l31] = o[dt][r];
        }
        if (hi == 0) lsp[qh * 32 + l31] = ls;
    }
    __syncthreads();
    if (kh == 0) {
        const float lt = ls + lsp[qh * 32 + l31];
        const int b = bh >> 4, hh = bh & 15;
        #pragma unroll
        for (int r = 0; r < 16; r++) {
            const int qlc = (r & 3) + 8 * (r >> 2) + 4 * hi;
            const float li = 1.0f / __shfl(lt, qlc);
            const size_t row = (size_t)b * SEQ + q0b + qh * 32 + qlc;
            #pragma unroll
            for (int dt = 0; dt < 2; dt++) {
                const float v = o[dt][r] + mrgO[(qh * 32 + qlc) * 66 + dt * 32 + l31];
                AO[row * D_MODEL + hh * HD + dt * 32 + l31] = (bf16_t)(v * li);
            }
        }
    }
}

// ---------------- launcher ----------------
extern "C" void kernel_launch(void* const* d_in, const int* in_sizes, int n_in,
                              void* d_out, int out_size, void* d_ws, size_t ws_size,
                              hipStream_t stream) {
    const float* x     = (const float*)d_in[0];
    const float* w_qkv = (const float*)d_in[1];
    const float* w_o   = (const float*)d_in[2];
    const int*   tpos  = (const int*)d_in[3];
    float*       out   = (float*)d_out;

    char* ws = (char*)d_ws;
    bf16_t* xb  = (bf16_t*)(ws);                 //  8 MB
    bf16_t* wqb = (bf16_t*)(ws + 8388608);       //  6 MB
    bf16_t* wob = (bf16_t*)(ws + 14680064);      //  2 MB
    bf16_t* qkv = (bf16_t*)(ws + 16777216);      // 24 MB
    bf16_t* Qh  = (bf16_t*)(ws + 41943040);      //  8 MB
    bf16_t* Kh  = (bf16_t*)(ws + 50331648);      //  8 MB
    bf16_t* VT  = (bf16_t*)(ws + 58720256);      //  8 MB
    bf16_t* AO  = (bf16_t*)(ws + 67108864);      //  8 MB

    cvt_all<<<8192, 256, 0, stream>>>(x, w_qkv, w_o, xb, wqb, wob);

    // qkv = x @ w_qkv^T : M=4096, N=3072, K=1024
    gemm_nt<bf16_t, 4><<<dim3(32, 24), 256, 0, stream>>>(xb, wqb, qkv, MROWS, QKVN, D_MODEL);

    rope_split<<<dim3(SEQ / 128, BATCH * NH), 256, 0, stream>>>(qkv, tpos, Qh, Kh, VT);

    flash_attn<<<1024, 256, 0, stream>>>(Qh, Kh, VT, AO);

    // out = AO @ w_o^T : M=4096, N=1024, K=1024 (fp32 out)
    gemm_nt<float, 2><<<dim3(32, 16), 256, 0, stream>>>(AO, wob, out, MROWS, D_MODEL, D_MODEL);
}